// Round 2
// baseline (344.879 us; speedup 1.0000x reference)
//
#include <hip/hip_runtime.h>
#include <hip/hip_bf16.h>
#include <stdint.h>

#define NDIM 4096
#define BM 128
#define BN 128
#define BK 64            // 8 chunks of 8 bf16 (16B vaults) per row

typedef __attribute__((ext_vector_type(8))) short bf16x8;
typedef __attribute__((ext_vector_type(8))) unsigned short u16x8;
typedef __attribute__((ext_vector_type(4))) float f32x4;   // native vec: ok for nontemporal builtins

__device__ __forceinline__ unsigned short f2bf(float f) {
    union { float f; uint32_t u; } v; v.f = f;
    uint32_t u = v.u;
    u += 0x7FFFu + ((u >> 16) & 1u);   // round-to-nearest-even
    return (unsigned short)(u >> 16);
}

// Chunks per tile by diagonal distance d: caps every block at <=16 BK-steps.
__device__ __host__ __forceinline__ int chunks_of(int d) {
    return (d >= 24) ? 4 : (d >= 16) ? 3 : (d >= 8) ? 2 : 1;
}

// --- Fused prep kernel ---
// blocks [0,2048):       A (fp32) -> triu-masked bf16 row-major
// blocks [2048,4096):    B -> triu-masked bf16 transposed Bt[c][k]
// blocks [4096,4892):    zero-fill C: all 496 strictly-lower tiles + the 300
//                        multi-chunk true tiles (d>=8) that trigemm atomically
//                        accumulates into. (C is 0xAA-poisoned each call.)
__global__ __launch_bounds__(256) void prep_kernel(const float* __restrict__ A,
                                                   const float* __restrict__ B,
                                                   unsigned short* __restrict__ Abf,
                                                   unsigned short* __restrict__ Bt,
                                                   float* __restrict__ C) {
    __shared__ float lds[32 * 65];
    const int b   = blockIdx.x;
    const int tid = threadIdx.x;

    if (b < 2048) {
        #pragma unroll
        for (int it = 0; it < 4; ++it) {
            int idx = b * 8192 + it * 2048 + tid * 8;
            int row = idx >> 12;
            int col = idx & 4095;
            f32x4 v0 = __builtin_nontemporal_load((const f32x4*)(A + idx));
            f32x4 v1 = __builtin_nontemporal_load((const f32x4*)(A + idx + 4));
            u16x8 o;
            o[0] = (col + 0 >= row) ? f2bf(v0.x) : (unsigned short)0;
            o[1] = (col + 1 >= row) ? f2bf(v0.y) : (unsigned short)0;
            o[2] = (col + 2 >= row) ? f2bf(v0.z) : (unsigned short)0;
            o[3] = (col + 3 >= row) ? f2bf(v0.w) : (unsigned short)0;
            o[4] = (col + 4 >= row) ? f2bf(v1.x) : (unsigned short)0;
            o[5] = (col + 5 >= row) ? f2bf(v1.y) : (unsigned short)0;
            o[6] = (col + 6 >= row) ? f2bf(v1.z) : (unsigned short)0;
            o[7] = (col + 7 >= row) ? f2bf(v1.w) : (unsigned short)0;
            *(u16x8*)(Abf + idx) = o;
        }
    } else if (b < 4096) {
        // B transpose+convert: block covers 64 k-rows x 128 c-cols as 4 sub-tiles
        int tb = b - 2048;
        int k0 = (tb >> 5) * 64;           // 64 k-groups
        int c0 = (tb & 31) * 128;          // 32 c-groups
        #pragma unroll
        for (int s = 0; s < 4; ++s) {
            int c0s = c0 + s * 32;
            #pragma unroll
            for (int p = 0; p < 2; ++p) {
                int kr = p * 32 + (tid >> 3);
                int cc = (tid & 7) * 4;
                f32x4 v = __builtin_nontemporal_load(
                    (const f32x4*)(B + (size_t)(k0 + kr) * NDIM + c0s + cc));
                lds[(cc + 0) * 65 + kr] = v.x;
                lds[(cc + 1) * 65 + kr] = v.y;
                lds[(cc + 2) * 65 + kr] = v.z;
                lds[(cc + 3) * 65 + kr] = v.w;
            }
            __syncthreads();
            int c  = tid >> 3;
            int ks = (tid & 7) * 8;
            u16x8 o;
            #pragma unroll
            for (int j = 0; j < 8; ++j) {
                float f = lds[c * 65 + ks + j];
                o[j] = (k0 + ks + j <= c0s + c) ? f2bf(f) : (unsigned short)0;
            }
            *(u16x8*)(Bt + (size_t)(c0s + c) * NDIM + k0 + ks) = o;
            __syncthreads();
        }
    } else {
        // zero-fill one 128x128 tile of C
        int z = b - 4096;
        int tr, tc;
        if (z < 496) {
            // strictly-lower (mirror) tile #z: (r,c), r>c, z = r(r-1)/2 + c
            int r = 1; while (z >= r) { z -= r; ++r; }
            tr = r; tc = z;
        } else {
            // multi-chunk true tile: d = 8..31, bi within
            z -= 496;
            int d2 = 8; while (z >= 32 - d2) { z -= 32 - d2; ++d2; }
            tr = z; tc = z + d2;
        }
        float* Z = C + (size_t)(tr * 128) * NDIM + tc * 128;
        const f32x4 zz = {0.f, 0.f, 0.f, 0.f};
        #pragma unroll
        for (int t = 0; t < 16; ++t) {
            int off = (t * 256 + tid) * 4;
            int rr = off >> 7, cc = off & 127;
            __builtin_nontemporal_store(zz, (f32x4*)(Z + (size_t)rr * NDIM + cc));
        }
    }
}

// --- Triangular bf16 MFMA GEMM, uniform K-chunks (<=16 BK-steps/block) ---
// Tiles enumerated d = bj-bi descending (LPT). Tile (d) split into chunks_of(d)
// K-chunks; multi-chunk tiles accumulate via native f32 atomic-add into the
// pre-zeroed true tile (prep zeroes them); single-chunk tiles plain-store.
// 1000 blocks, 4 resident/CU. No reduce kernel needed.
__global__ __launch_bounds__(256, 4) void trigemm_kernel(
        const unsigned short* __restrict__ Abf,
        const unsigned short* __restrict__ Bt,
        float* __restrict__ C) {
    int rem = blockIdx.x, d = 31, nc = 4, g = 4;   // d=31 group: (32-31)*4
    while (rem >= g) {
        rem -= g; --d;
        nc = chunks_of(d);
        g  = (32 - d) * nc;
    }
    const int bi = rem / nc, q = rem - bi * nc;
    const int bj = bi + d;
    const int S = 2 * (d + 1);                     // total BK-steps of this tile
    const int base = S / nc, extra = S - base * nc;
    const int nsteps = base + (q < extra ? 1 : 0);
    const int start  = q * base + (q < extra ? q : extra);

    __shared__ unsigned short As[BM * BK];   // 16 KB
    __shared__ unsigned short Bs[BN * BK];   // 16 KB

    const int tid  = threadIdx.x;
    const int wave = tid >> 6, lane = tid & 63;
    const int wm = wave >> 1, wn = wave & 1;
    const int m_l = lane & 15, kh = lane >> 4;
    const int ml7 = m_l & 7;

    f32x4 acc[4][4] = {};

    const int i0 = bi * BM, j0 = bj * BN;
    const int k_start = i0 + start * BK;

    const unsigned short* Ar = Abf + (size_t)i0 * NDIM;
    const unsigned short* Br = Bt  + (size_t)j0 * NDIM;

    // staging map: pass p covers row r0+32p, chunk kc (16B); xor depends only on r0&7
    const int r0 = tid >> 3, kc = tid & 7;
    const int woff = r0 * BK + ((kc ^ (r0 & 7)) * 8);       // LDS short idx, + p*2048
    const size_t g0 = (size_t)r0 * NDIM + kc * 8;           // + p*32*NDIM + koff

    u16x8 a0_0, a0_1, a0_2, a0_3, b0_0, b0_1, b0_2, b0_3;
    u16x8 a1_0, a1_1, a1_2, a1_3, b1_0, b1_1, b1_2, b1_3;

#define LOAD_STAGE(AN, BN_, koff) do {                                          \
        const size_t _g = g0 + (size_t)(koff);                                  \
        AN##_0 = *(const u16x8*)(Ar + _g);                                      \
        AN##_1 = *(const u16x8*)(Ar + _g + (size_t)32 * NDIM);                  \
        AN##_2 = *(const u16x8*)(Ar + _g + (size_t)64 * NDIM);                  \
        AN##_3 = *(const u16x8*)(Ar + _g + (size_t)96 * NDIM);                  \
        BN_##_0 = *(const u16x8*)(Br + _g);                                     \
        BN_##_1 = *(const u16x8*)(Br + _g + (size_t)32 * NDIM);                 \
        BN_##_2 = *(const u16x8*)(Br + _g + (size_t)64 * NDIM);                 \
        BN_##_3 = *(const u16x8*)(Br + _g + (size_t)96 * NDIM);                 \
    } while (0)

#define WRITE_STAGE(AN, BN_) do {                                               \
        *(u16x8*)&As[woff         ] = AN##_0;                                   \
        *(u16x8*)&As[woff + 1*2048] = AN##_1;                                   \
        *(u16x8*)&As[woff + 2*2048] = AN##_2;                                   \
        *(u16x8*)&As[woff + 3*2048] = AN##_3;                                   \
        *(u16x8*)&Bs[woff         ] = BN_##_0;                                  \
        *(u16x8*)&Bs[woff + 1*2048] = BN_##_1;                                  \
        *(u16x8*)&Bs[woff + 2*2048] = BN_##_2;                                  \
        *(u16x8*)&Bs[woff + 3*2048] = BN_##_3;                                  \
    } while (0)

#define COMPUTE() do {                                                          \
        _Pragma("unroll")                                                       \
        for (int s = 0; s < 2; ++s) {                                           \
            const int xk = ((s * 4 + kh) ^ ml7) * 8;                            \
            bf16x8 bfr[4], afr[4];                                              \
            _Pragma("unroll")                                                   \
            for (int nt = 0; nt < 4; ++nt)                                      \
                bfr[nt] = *(const bf16x8*)&Bs[(wn*64 + nt*16 + m_l)*BK + xk];   \
            _Pragma("unroll")                                                   \
            for (int mt = 0; mt < 4; ++mt)                                      \
                afr[mt] = *(const bf16x8*)&As[(wm*64 + mt*16 + m_l)*BK + xk];   \
            _Pragma("unroll")                                                   \
            for (int mt = 0; mt < 4; ++mt)                                      \
                _Pragma("unroll")                                               \
                for (int nt = 0; nt < 4; ++nt)                                  \
                    acc[mt][nt] = __builtin_amdgcn_mfma_f32_16x16x32_bf16(      \
                        afr[mt], bfr[nt], acc[mt][nt], 0, 0, 0);                \
        }                                                                       \
    } while (0)

    LOAD_STAGE(a0, b0, k_start);
    if (nsteps > 1) LOAD_STAGE(a1, b1, k_start + BK);

    int it = 0;
    for (; it + 2 <= nsteps; it += 2) {
        WRITE_STAGE(a0, b0);                 // vmcnt wait: loads issued 2 iters ago
        if (it + 2 < nsteps) LOAD_STAGE(a0, b0, k_start + (it + 2) * BK);
        __syncthreads();
        COMPUTE();
        __syncthreads();
        WRITE_STAGE(a1, b1);
        if (it + 3 < nsteps) LOAD_STAGE(a1, b1, k_start + (it + 3) * BK);
        __syncthreads();
        COMPUTE();
        __syncthreads();
    }
    if (it < nsteps) {                       // odd K-step tail (some chunks are odd)
        WRITE_STAGE(a0, b0);
        __syncthreads();
        COMPUTE();
        __syncthreads();
    }
#undef LOAD_STAGE
#undef WRITE_STAGE
#undef COMPUTE

    // Epilogue: C/D layout col=lane&15, row=(lane>>4)*4+reg (m89/m91-verified).
    // nc==1: full plain store (covers sub-diagonal zeros too).
    // nc>=2: native f32 atomic-add into pre-zeroed true tile (device scope).
    float* Cbase = C + (size_t)i0 * NDIM + j0;
    if (nc == 1) {
        #pragma unroll
        for (int mt = 0; mt < 4; ++mt)
            #pragma unroll
            for (int nt = 0; nt < 4; ++nt)
                #pragma unroll
                for (int r = 0; r < 4; ++r) {
                    int row = wm * 64 + mt * 16 + kh * 4 + r;
                    int col = wn * 64 + nt * 16 + m_l;
                    __builtin_nontemporal_store(acc[mt][nt][r],
                                                Cbase + (size_t)row * NDIM + col);
                }
    } else {
        #pragma unroll
        for (int mt = 0; mt < 4; ++mt)
            #pragma unroll
            for (int nt = 0; nt < 4; ++nt)
                #pragma unroll
                for (int r = 0; r < 4; ++r) {
                    int row = wm * 64 + mt * 16 + kh * 4 + r;
                    int col = wn * 64 + nt * 16 + m_l;
                    __hip_atomic_fetch_add(Cbase + (size_t)row * NDIM + col,
                                           acc[mt][nt][r],
                                           __ATOMIC_RELAXED,
                                           __HIP_MEMORY_SCOPE_AGENT);
                }
    }
}

extern "C" void kernel_launch(void* const* d_in, const int* in_sizes, int n_in,
                              void* d_out, int out_size, void* d_ws, size_t ws_size,
                              hipStream_t stream) {
    const float* A = (const float*)d_in[0];
    const float* B = (const float*)d_in[1];
    float* C = (float*)d_out;

    unsigned short* Abf = (unsigned short*)d_ws;                   // 32 MB
    unsigned short* Bt  = Abf + (size_t)NDIM * NDIM;               // 32 MB

    // 4096 convert blocks + 796 C-zero blocks (496 mirror + 300 multi-chunk true)
    prep_kernel<<<4892, 256, 0, stream>>>(A, B, Abf, Bt, C);
    // blocks: sum over d of (32-d)*chunks_of(d) = 228 + 328 + 300 + 144 = 1000
    trigemm_kernel<<<1000, 256, 0, stream>>>(Abf, Bt, C);
}

// Round 3
// 223.967 us; speedup vs baseline: 1.5399x; 1.5399x over previous
//
#include <hip/hip_runtime.h>
#include <hip/hip_bf16.h>
#include <stdint.h>

#define NDIM 4096
#define BM 128
#define BN 128
#define BK 64            // 8 chunks of 8 bf16 (16B vaults) per row

typedef __attribute__((ext_vector_type(8))) short bf16x8;
typedef __attribute__((ext_vector_type(8))) unsigned short u16x8;
typedef __attribute__((ext_vector_type(4))) float f32x4;   // native vec: ok for nontemporal builtins

__device__ __forceinline__ unsigned short f2bf(float f) {
    union { float f; uint32_t u; } v; v.f = f;
    uint32_t u = v.u;
    u += 0x7FFFu + ((u >> 16) & 1u);   // round-to-nearest-even
    return (unsigned short)(u >> 16);
}

// Chunks per tile by diagonal distance d: caps every block at <=16 BK-steps.
// Partial buffers needed: sum (32-d)*(chunks-1) = 108+200+164 = 472 <= 496 mirrors.
__device__ __host__ __forceinline__ int chunks_of(int d) {
    return (d >= 24) ? 4 : (d >= 16) ? 3 : (d >= 8) ? 2 : 1;
}

// --- Fused prep kernel (upper-block-triangular only: 99 MB vs 192 MB) ---
// blocks [0,528):      A upper 128x128 tiles -> triu-masked bf16 (row-major)
// blocks [528,1584):   B 64k x 128c blocks with k-block <= c-block ->
//                      triu-masked bf16 transposed Bt[c][k]
// trigemm never reads A at k < row-block start, nor Bt at k >= col-block end.
__global__ __launch_bounds__(256) void prep_kernel(const float* __restrict__ A,
                                                   const float* __restrict__ B,
                                                   unsigned short* __restrict__ Abf,
                                                   unsigned short* __restrict__ Bt) {
    __shared__ float lds[32 * 65];
    const int b   = blockIdx.x;
    const int tid = threadIdx.x;

    if (b < 528) {
        // A upper tile #b: (R, Kb), Kb >= R
        int bb = b, R = 0;
        while (bb >= 32 - R) { bb -= 32 - R; ++R; }
        const int Kb = R + bb;
        const int i0 = R * 128, k0 = Kb * 128;
        const bool diag = (R == Kb);
        #pragma unroll
        for (int t = 0; t < 8; ++t) {
            int e  = (t * 256 + tid) * 8;          // 0..16383 within tile
            int tr = e >> 7, tc = e & 127;
            const size_t g = (size_t)(i0 + tr) * NDIM + k0 + tc;
            f32x4 v0 = __builtin_nontemporal_load((const f32x4*)(A + g));
            f32x4 v1 = __builtin_nontemporal_load((const f32x4*)(A + g + 4));
            u16x8 o;
            #pragma unroll
            for (int j = 0; j < 8; ++j) {
                float f = (j < 4) ? v0[j] : v1[j - 4];
                o[j] = (!diag || (tc + j >= tr)) ? f2bf(f) : (unsigned short)0;
            }
            *(u16x8*)(Abf + g) = o;
        }
    } else {
        // B block: 64 k-rows x 128 c-cols, only k64-block <= diagonal of c-block
        int tb = b - 528, cb = 0;
        while (tb >= 2 * (cb + 1)) { tb -= 2 * (cb + 1); ++cb; }
        const int k0 = tb * 64;            // k64-block 0 .. 2*cb+1
        const int c0 = cb * 128;
        #pragma unroll
        for (int s = 0; s < 4; ++s) {
            int c0s = c0 + s * 32;
            #pragma unroll
            for (int p = 0; p < 2; ++p) {
                int kr = p * 32 + (tid >> 3);
                int cc = (tid & 7) * 4;
                f32x4 v = __builtin_nontemporal_load(
                    (const f32x4*)(B + (size_t)(k0 + kr) * NDIM + c0s + cc));
                lds[(cc + 0) * 65 + kr] = v.x;
                lds[(cc + 1) * 65 + kr] = v.y;
                lds[(cc + 2) * 65 + kr] = v.z;
                lds[(cc + 3) * 65 + kr] = v.w;
            }
            __syncthreads();
            int c  = tid >> 3;
            int ks = (tid & 7) * 8;
            u16x8 o;
            #pragma unroll
            for (int j = 0; j < 8; ++j) {
                float f = lds[c * 65 + ks + j];
                o[j] = (k0 + ks + j <= c0s + c) ? f2bf(f) : (unsigned short)0;
            }
            *(u16x8*)(Bt + (size_t)(c0s + c) * NDIM + k0 + ks) = o;
            __syncthreads();
        }
    }
}

// --- Triangular bf16 MFMA GEMM, uniform K-chunks (<=16 BK-steps/block) ---
// Tiles enumerated d = bj-bi descending (LPT). Tile split into chunks_of(d)
// K-chunks. Chunk q==0 plain-stores the true tile; chunks q>=1 plain-store
// their partial into a dedicated mirror (strictly-lower) C tile; treduce
// merges partials into true tiles and zeroes ALL 496 mirror tiles.
// No atomics. __launch_bounds__(256,2): VGPR=100, no spills (round-2 lesson).
__global__ __launch_bounds__(256, 2) void trigemm_kernel(
        const unsigned short* __restrict__ Abf,
        const unsigned short* __restrict__ Bt,
        float* __restrict__ C) {
    int rem = blockIdx.x, d = 31, nc = 4, g = 4, pbase = 0;
    while (rem >= g) {
        rem -= g;
        pbase += (32 - d) * (nc - 1);
        --d;
        nc = chunks_of(d);
        g  = (32 - d) * nc;
    }
    const int bi = rem / nc, q = rem - bi * nc;
    const int bj = bi + d;
    const int S = 2 * (d + 1);                     // total BK-steps of this tile
    const int base = S / nc, extra = S - base * nc;
    const int nsteps = base + (q < extra ? 1 : 0);
    const int start  = q * base + (q < extra ? q : extra);

    __shared__ unsigned short As[BM * BK];   // 16 KB
    __shared__ unsigned short Bs[BN * BK];   // 16 KB

    const int tid  = threadIdx.x;
    const int wave = tid >> 6, lane = tid & 63;
    const int wm = wave >> 1, wn = wave & 1;
    const int m_l = lane & 15, kh = lane >> 4;
    const int ml7 = m_l & 7;

    f32x4 acc[4][4] = {};

    const int i0 = bi * BM, j0 = bj * BN;
    const int k_start = i0 + start * BK;

    const unsigned short* Ar = Abf + (size_t)i0 * NDIM;
    const unsigned short* Br = Bt  + (size_t)j0 * NDIM;

    // staging map: pass p covers row r0+32p, chunk kc (16B); xor depends only on r0&7
    const int r0 = tid >> 3, kc = tid & 7;
    const int woff = r0 * BK + ((kc ^ (r0 & 7)) * 8);       // LDS short idx, + p*2048
    const size_t g0 = (size_t)r0 * NDIM + kc * 8;           // + p*32*NDIM + koff

    u16x8 a0_0, a0_1, a0_2, a0_3, b0_0, b0_1, b0_2, b0_3;
    u16x8 a1_0, a1_1, a1_2, a1_3, b1_0, b1_1, b1_2, b1_3;

#define LOAD_STAGE(AN, BN_, koff) do {                                          \
        const size_t _g = g0 + (size_t)(koff);                                  \
        AN##_0 = *(const u16x8*)(Ar + _g);                                      \
        AN##_1 = *(const u16x8*)(Ar + _g + (size_t)32 * NDIM);                  \
        AN##_2 = *(const u16x8*)(Ar + _g + (size_t)64 * NDIM);                  \
        AN##_3 = *(const u16x8*)(Ar + _g + (size_t)96 * NDIM);                  \
        BN_##_0 = *(const u16x8*)(Br + _g);                                     \
        BN_##_1 = *(const u16x8*)(Br + _g + (size_t)32 * NDIM);                 \
        BN_##_2 = *(const u16x8*)(Br + _g + (size_t)64 * NDIM);                 \
        BN_##_3 = *(const u16x8*)(Br + _g + (size_t)96 * NDIM);                 \
    } while (0)

#define WRITE_STAGE(AN, BN_) do {                                               \
        *(u16x8*)&As[woff         ] = AN##_0;                                   \
        *(u16x8*)&As[woff + 1*2048] = AN##_1;                                   \
        *(u16x8*)&As[woff + 2*2048] = AN##_2;                                   \
        *(u16x8*)&As[woff + 3*2048] = AN##_3;                                   \
        *(u16x8*)&Bs[woff         ] = BN_##_0;                                  \
        *(u16x8*)&Bs[woff + 1*2048] = BN_##_1;                                  \
        *(u16x8*)&Bs[woff + 2*2048] = BN_##_2;                                  \
        *(u16x8*)&Bs[woff + 3*2048] = BN_##_3;                                  \
    } while (0)

#define COMPUTE() do {                                                          \
        _Pragma("unroll")                                                       \
        for (int s = 0; s < 2; ++s) {                                           \
            const int xk = ((s * 4 + kh) ^ ml7) * 8;                            \
            bf16x8 bfr[4], afr[4];                                              \
            _Pragma("unroll")                                                   \
            for (int nt = 0; nt < 4; ++nt)                                      \
                bfr[nt] = *(const bf16x8*)&Bs[(wn*64 + nt*16 + m_l)*BK + xk];   \
            _Pragma("unroll")                                                   \
            for (int mt = 0; mt < 4; ++mt)                                      \
                afr[mt] = *(const bf16x8*)&As[(wm*64 + mt*16 + m_l)*BK + xk];   \
            _Pragma("unroll")                                                   \
            for (int mt = 0; mt < 4; ++mt)                                      \
                _Pragma("unroll")                                               \
                for (int nt = 0; nt < 4; ++nt)                                  \
                    acc[mt][nt] = __builtin_amdgcn_mfma_f32_16x16x32_bf16(      \
                        afr[mt], bfr[nt], acc[mt][nt], 0, 0, 0);                \
        }                                                                       \
    } while (0)

    LOAD_STAGE(a0, b0, k_start);
    if (nsteps > 1) LOAD_STAGE(a1, b1, k_start + BK);

    int it = 0;
    for (; it + 2 <= nsteps; it += 2) {
        WRITE_STAGE(a0, b0);                 // vmcnt wait: loads issued 2 iters ago
        if (it + 2 < nsteps) LOAD_STAGE(a0, b0, k_start + (it + 2) * BK);
        __syncthreads();
        COMPUTE();
        __syncthreads();
        WRITE_STAGE(a1, b1);
        if (it + 3 < nsteps) LOAD_STAGE(a1, b1, k_start + (it + 3) * BK);
        __syncthreads();
        COMPUTE();
        __syncthreads();
    }
    if (it < nsteps) {                       // odd K-step tail (some chunks are odd)
        WRITE_STAGE(a0, b0);
        __syncthreads();
        COMPUTE();
        __syncthreads();
    }
#undef LOAD_STAGE
#undef WRITE_STAGE
#undef COMPUTE

    // Epilogue: C/D layout col=lane&15, row=(lane>>4)*4+reg (m89/m91-verified).
    // q==0 -> true tile; q>=1 -> partial into mirror tile #(pbase+bi*(nc-1)+q-1).
    float* Cbase;
    if (q == 0) {
        Cbase = C + (size_t)i0 * NDIM + j0;
    } else {
        int pp = pbase + bi * (nc - 1) + (q - 1);
        int r = 1;
        while (pp >= r) { pp -= r; ++r; }    // lower tile (r, pp), r > pp
        Cbase = C + (size_t)(r * 128) * NDIM + pp * 128;
    }
    #pragma unroll
    for (int mt = 0; mt < 4; ++mt)
        #pragma unroll
        for (int nt = 0; nt < 4; ++nt)
            #pragma unroll
            for (int r = 0; r < 4; ++r) {
                int row = wm * 64 + mt * 16 + kh * 4 + r;
                int col = wn * 64 + nt * 16 + m_l;
                __builtin_nontemporal_store(acc[mt][nt][r],
                                            Cbase + (size_t)row * NDIM + col);
            }
}

// --- Merge partials and zero all mirrors ---
// blocks [0,1200): quarter (32 rows x 128 cols) of each of the 300 multi-chunk
//                  true tiles: true += sum(partials); zero partial quarters.
// blocks [1200,1224): zero the 24 unused mirror tiles (indices 472..495).
__global__ __launch_bounds__(256) void treduce_kernel(float* __restrict__ C) {
    const int b   = blockIdx.x;
    const int tid = threadIdx.x;
    const f32x4 z = {0.f, 0.f, 0.f, 0.f};

    if (b < 1200) {
        const int t = b >> 2, qq = b & 3;
        int rem = t, d = 31, nc = 4, pbase = 0;
        while (rem >= 32 - d) {
            rem -= 32 - d;
            pbase += (32 - d) * (nc - 1);
            --d;
            nc = chunks_of(d);
        }
        const int bi = rem, bj = bi + d;
        const int npart = nc - 1;            // 1..3 (d >= 8 here)
        const int p0 = pbase + bi * npart;

        float* T = C + (size_t)(bi * 128) * NDIM + bj * 128;
        f32x4 sum[4];
        #pragma unroll
        for (int tt = 0; tt < 4; ++tt) {
            int e = (tt * 256 + tid) * 4;
            int rr = qq * 32 + (e >> 7), cc = e & 127;
            sum[tt] = *(const f32x4*)(T + (size_t)rr * NDIM + cc);
        }
        for (int j = 0; j < npart; ++j) {
            int pp = p0 + j, r = 1;
            while (pp >= r) { pp -= r; ++r; }
            float* P = C + (size_t)(r * 128) * NDIM + pp * 128;
            #pragma unroll
            for (int tt = 0; tt < 4; ++tt) {
                int e = (tt * 256 + tid) * 4;
                int rr = qq * 32 + (e >> 7), cc = e & 127;
                f32x4 v = __builtin_nontemporal_load(
                    (const f32x4*)(P + (size_t)rr * NDIM + cc));
                sum[tt] = sum[tt] + v;
                __builtin_nontemporal_store(z, (f32x4*)(P + (size_t)rr * NDIM + cc));
            }
        }
        #pragma unroll
        for (int tt = 0; tt < 4; ++tt) {
            int e = (tt * 256 + tid) * 4;
            int rr = qq * 32 + (e >> 7), cc = e & 127;
            __builtin_nontemporal_store(sum[tt], (f32x4*)(T + (size_t)rr * NDIM + cc));
        }
    } else {
        int pp = 472 + (b - 1200), r = 1;
        while (pp >= r) { pp -= r; ++r; }
        float* P = C + (size_t)(r * 128) * NDIM + pp * 128;
        #pragma unroll
        for (int t = 0; t < 16; ++t) {
            int off = (t * 256 + tid) * 4;
            int rr = off >> 7, cc = off & 127;
            __builtin_nontemporal_store(z, (f32x4*)(P + (size_t)rr * NDIM + cc));
        }
    }
}

extern "C" void kernel_launch(void* const* d_in, const int* in_sizes, int n_in,
                              void* d_out, int out_size, void* d_ws, size_t ws_size,
                              hipStream_t stream) {
    const float* A = (const float*)d_in[0];
    const float* B = (const float*)d_in[1];
    float* C = (float*)d_out;

    unsigned short* Abf = (unsigned short*)d_ws;                   // 32 MB region
    unsigned short* Bt  = Abf + (size_t)NDIM * NDIM;               // 32 MB region

    // 528 A-tiles + 1056 B-blocks (upper-block-triangular only)
    prep_kernel<<<1584, 256, 0, stream>>>(A, B, Abf, Bt);
    // sum over d of (32-d)*chunks_of(d) = 144 + 300 + 328 + 228 = 1000
    trigemm_kernel<<<1000, 256, 0, stream>>>(Abf, Bt, C);
    // 300 multi-chunk tiles x 4 quarters + 24 unused-mirror zero blocks
    treduce_kernel<<<1224, 256, 0, stream>>>(C);
}

// Round 4
// 210.084 us; speedup vs baseline: 1.6416x; 1.0661x over previous
//
#include <hip/hip_runtime.h>
#include <hip/hip_bf16.h>
#include <stdint.h>

#define NDIM 4096
#define BM 128
#define BN 128
#define BK 64              // K-step: 128 rows x 64 k x bf16 = 16 KB panel chunk
#define STEP_SHORTS 8192   // shorts per packed panel step-chunk

typedef __attribute__((ext_vector_type(8))) short bf16x8;
typedef __attribute__((ext_vector_type(8))) unsigned short u16x8;
typedef __attribute__((ext_vector_type(4))) float f32x4;

__device__ __forceinline__ unsigned short f2bf(float f) {
    union { float f; uint32_t u; } v; v.f = f;
    uint32_t u = v.u;
    u += 0x7FFFu + ((u >> 16) & 1u);   // round-to-nearest-even
    return (unsigned short)(u >> 16);
}

// Packed panel step bases (in 16KB step-chunks):
// A panel bi: k in [128*bi, 4096) -> 64-2*bi steps. Total 1056 steps = 16.5 MB.
__device__ __forceinline__ int stepbase_A(int bi) { return bi * (65 - bi); }
// B panel bj: k in [0, 128*(bj+1)) -> 2*(bj+1) steps. Total 1056 steps.
__device__ __forceinline__ int stepbase_B(int bj) { return bj * (bj + 1); }

// --- Prep: fp32 -> triu-masked bf16 PACKED PANELS (pre-swizzled to the exact
// staging thread order, so trigemm reads each K-step as one sequential 16 KB).
// Element (row r in block, k-step s, k6): p = r>>5, tid2 = ((r&31)<<3)|(k6>>3),
// stored at step*8192 + p*2048 + tid2*8 + (k6&7).
// blocks [0,528):      A upper 128x128 tiles
// blocks [528,1584):   B 64k x 128c blocks (k-block <= diag of c-block), transposed
__global__ __launch_bounds__(256) void prep_kernel(const float* __restrict__ A,
                                                   const float* __restrict__ B,
                                                   unsigned short* __restrict__ Abf,
                                                   unsigned short* __restrict__ Bt) {
    __shared__ float lds[32 * 65];
    const int b   = blockIdx.x;
    const int tid = threadIdx.x;

    if (b < 528) {
        // A upper tile #b: (R, Kb), Kb >= R; covers panel-A[R] steps 2(Kb-R)..+1
        int bb = b, R = 0;
        while (bb >= 32 - R) { bb -= 32 - R; ++R; }
        const int Kb = R + bb;
        const int i0 = R * 128, k0 = Kb * 128;
        const bool diag = (R == Kb);
        const int sbase = stepbase_A(R) + 2 * (Kb - R);
        #pragma unroll
        for (int t = 0; t < 8; ++t) {
            int e  = (t * 256 + tid) * 8;          // 0..16383 within tile
            int tr = e >> 7, tc = e & 127;         // tc multiple of 8
            const size_t g = (size_t)(i0 + tr) * NDIM + k0 + tc;
            f32x4 v0 = __builtin_nontemporal_load((const f32x4*)(A + g));
            f32x4 v1 = __builtin_nontemporal_load((const f32x4*)(A + g + 4));
            u16x8 o;
            #pragma unroll
            for (int j = 0; j < 8; ++j) {
                float f = (j < 4) ? v0[j] : v1[j - 4];
                o[j] = (!diag || (tc + j >= tr)) ? f2bf(f) : (unsigned short)0;
            }
            const int soff = sbase + (tc >> 6);
            const int p    = tr >> 5;
            const int tid2 = ((tr & 31) << 3) | ((tc & 63) >> 3);
            *(u16x8*)(Abf + (size_t)soff * STEP_SHORTS + p * 2048 + tid2 * 8) = o;
        }
    } else {
        // B block: 64 k-rows x 128 c-cols -> panel-B[cb] step (tb), transposed
        int tb = b - 528, cb = 0;
        while (tb >= 2 * (cb + 1)) { tb -= 2 * (cb + 1); ++cb; }
        const int k0 = tb * 64;
        const int c0 = cb * 128;
        const size_t sb = (size_t)(stepbase_B(cb) + tb) * STEP_SHORTS;
        #pragma unroll
        for (int s = 0; s < 4; ++s) {
            int c0s = c0 + s * 32;
            #pragma unroll
            for (int p = 0; p < 2; ++p) {
                int kr = p * 32 + (tid >> 3);
                int cc = (tid & 7) * 4;
                f32x4 v = __builtin_nontemporal_load(
                    (const f32x4*)(B + (size_t)(k0 + kr) * NDIM + c0s + cc));
                lds[(cc + 0) * 65 + kr] = v.x;
                lds[(cc + 1) * 65 + kr] = v.y;
                lds[(cc + 2) * 65 + kr] = v.z;
                lds[(cc + 3) * 65 + kr] = v.w;
            }
            __syncthreads();
            int c  = tid >> 3;                      // col within 32-group
            int ks = (tid & 7) * 8;
            u16x8 o;
            #pragma unroll
            for (int j = 0; j < 8; ++j) {
                float f = lds[c * 65 + ks + j];
                o[j] = (k0 + ks + j <= c0s + c) ? f2bf(f) : (unsigned short)0;
            }
            // c_in_block = s*32 + c -> p = s, tid2 = (c<<3)|(tid&7) = tid
            *(u16x8*)(Bt + sb + s * 2048 + tid * 8) = o;
            __syncthreads();
        }
    }
}

// --- Triangular bf16 MFMA GEMM on packed panels ---
// bj-major descending enumeration (LPT + Bt-panel L2 sharing between adjacent
// blocks). Tiles with d = bj-bi >= 16 K-split in 2: khalf 1 -> true tile,
// khalf 0 -> partial into mirror tile (bj,bi); treduce merges. Unsplit tiles
// plain-store true tile and zero-fill their mirror. Max 32 steps/block.
__global__ __launch_bounds__(256, 2) void trigemm_kernel(
        const unsigned short* __restrict__ Abf,
        const unsigned short* __restrict__ Bt,
        float* __restrict__ C) {
    // group size per bj: bj+1 tiles, +max(0,bj-15) extra (split) blocks
    int rank = blockIdx.x;
    int bj = 31, g = 48;                     // bj=31: 2*31-14
    while (rank >= g) {
        rank -= g; --bj;
        g = (bj >= 16) ? (2 * bj - 14) : (bj + 1);
    }
    const int nsplit = (bj >= 16) ? (bj - 15) : 0;
    int bi, khalf, split;
    if (rank < 2 * nsplit) { bi = rank >> 1; khalf = rank & 1; split = 1; }
    else                   { bi = nsplit + (rank - 2 * nsplit); khalf = 0; split = 0; }
    const int d = bj - bi;
    const int nsteps = split ? (d + 1) : 2 * (d + 1);   // 2..32

    __shared__ unsigned short As[BM * BK];   // 16 KB
    __shared__ unsigned short Bs[BN * BK];   // 16 KB

    const int tid  = threadIdx.x;
    const int wave = tid >> 6, lane = tid & 63;
    const int wm = wave >> 1, wn = wave & 1;
    const int m_l = lane & 15, kh = lane >> 4;
    const int ml7 = m_l & 7;

    f32x4 acc[4][4] = {};

    const int i0 = bi * BM, j0 = bj * BN;

    // Packed panel bases; chunk start = khalf*(d+1) local steps in.
    const unsigned short* ArS = Abf
        + ((size_t)(stepbase_A(bi) + khalf * (d + 1))) * STEP_SHORTS
        + (size_t)tid * 8;
    const unsigned short* BrS = Bt
        + ((size_t)(stepbase_B(bj) + 2 * bi + khalf * (d + 1))) * STEP_SHORTS
        + (size_t)tid * 8;

    // LDS scatter map (unchanged, verified): row r0 = tid>>3, chunk kc = tid&7
    const int r0 = tid >> 3, kc = tid & 7;
    const int woff = r0 * BK + ((kc ^ (r0 & 7)) * 8);

    u16x8 a0_0, a0_1, a0_2, a0_3, b0_0, b0_1, b0_2, b0_3;
    u16x8 a1_0, a1_1, a1_2, a1_3, b1_0, b1_1, b1_2, b1_3;

#define LOAD_STAGE(AN, BN_, s) do {                                             \
        const size_t _o = (size_t)(s) * STEP_SHORTS;                            \
        AN##_0 = *(const u16x8*)(ArS + _o);                                     \
        AN##_1 = *(const u16x8*)(ArS + _o + 2048);                              \
        AN##_2 = *(const u16x8*)(ArS + _o + 4096);                              \
        AN##_3 = *(const u16x8*)(ArS + _o + 6144);                              \
        BN_##_0 = *(const u16x8*)(BrS + _o);                                    \
        BN_##_1 = *(const u16x8*)(BrS + _o + 2048);                             \
        BN_##_2 = *(const u16x8*)(BrS + _o + 4096);                             \
        BN_##_3 = *(const u16x8*)(BrS + _o + 6144);                             \
    } while (0)

#define WRITE_STAGE(AN, BN_) do {                                               \
        *(u16x8*)&As[woff         ] = AN##_0;                                   \
        *(u16x8*)&As[woff + 1*2048] = AN##_1;                                   \
        *(u16x8*)&As[woff + 2*2048] = AN##_2;                                   \
        *(u16x8*)&As[woff + 3*2048] = AN##_3;                                   \
        *(u16x8*)&Bs[woff         ] = BN_##_0;                                  \
        *(u16x8*)&Bs[woff + 1*2048] = BN_##_1;                                  \
        *(u16x8*)&Bs[woff + 2*2048] = BN_##_2;                                  \
        *(u16x8*)&Bs[woff + 3*2048] = BN_##_3;                                  \
    } while (0)

#define COMPUTE() do {                                                          \
        _Pragma("unroll")                                                       \
        for (int s = 0; s < 2; ++s) {                                           \
            const int xk = ((s * 4 + kh) ^ ml7) * 8;                            \
            bf16x8 bfr[4], afr[4];                                              \
            _Pragma("unroll")                                                   \
            for (int nt = 0; nt < 4; ++nt)                                      \
                bfr[nt] = *(const bf16x8*)&Bs[(wn*64 + nt*16 + m_l)*BK + xk];   \
            _Pragma("unroll")                                                   \
            for (int mt = 0; mt < 4; ++mt)                                      \
                afr[mt] = *(const bf16x8*)&As[(wm*64 + mt*16 + m_l)*BK + xk];   \
            _Pragma("unroll")                                                   \
            for (int mt = 0; mt < 4; ++mt)                                      \
                _Pragma("unroll")                                               \
                for (int nt = 0; nt < 4; ++nt)                                  \
                    acc[mt][nt] = __builtin_amdgcn_mfma_f32_16x16x32_bf16(      \
                        afr[mt], bfr[nt], acc[mt][nt], 0, 0, 0);                \
        }                                                                       \
    } while (0)

    LOAD_STAGE(a0, b0, 0);
    if (nsteps > 1) LOAD_STAGE(a1, b1, 1);

    int it = 0;
    for (; it + 2 <= nsteps; it += 2) {
        WRITE_STAGE(a0, b0);                 // vmcnt wait: loads issued 2 iters ago
        if (it + 2 < nsteps) LOAD_STAGE(a0, b0, it + 2);
        __syncthreads();
        COMPUTE();
        __syncthreads();
        WRITE_STAGE(a1, b1);
        if (it + 3 < nsteps) LOAD_STAGE(a1, b1, it + 3);
        __syncthreads();
        COMPUTE();
        __syncthreads();
    }
    if (it < nsteps) {                       // odd step-count tail (split halves)
        WRITE_STAGE(a0, b0);
        __syncthreads();
        COMPUTE();
        __syncthreads();
    }
#undef LOAD_STAGE
#undef WRITE_STAGE
#undef COMPUTE

    // Epilogue: C/D layout col=lane&15, row=(lane>>4)*4+reg (m89/m91-verified).
    // split&&khalf==0 -> partial into mirror tile (bj,bi); else true tile.
    const bool to_mirror = split && (khalf == 0);
    float* Cbase = to_mirror ? (C + (size_t)j0 * NDIM + i0)
                             : (C + (size_t)i0 * NDIM + j0);
    #pragma unroll
    for (int mt = 0; mt < 4; ++mt)
        #pragma unroll
        for (int nt = 0; nt < 4; ++nt)
            #pragma unroll
            for (int r = 0; r < 4; ++r) {
                int row = wm * 64 + mt * 16 + kh * 4 + r;
                int col = wn * 64 + nt * 16 + m_l;
                __builtin_nontemporal_store(acc[mt][nt][r],
                                            Cbase + (size_t)row * NDIM + col);
            }
    // Mirror zero-fill for unsplit off-diagonal tiles (C is poisoned each call).
    if (!split && bi != bj) {
        float* Z = C + (size_t)j0 * NDIM + i0;
        f32x4 z = {0.f, 0.f, 0.f, 0.f};
        #pragma unroll
        for (int t = 0; t < 16; ++t) {
            int off = (t * 256 + tid) * 4;
            int rr = off >> 7, cc = off & 127;
            __builtin_nontemporal_store(z, (f32x4*)(Z + (size_t)rr * NDIM + cc));
        }
    }
}

// --- Merge split-tile partials: C[true] += C[mirror]; C[mirror] = 0 ---
// 136 split tiles (d >= 16), 4 blocks per tile (32-row quarter each).
__global__ __launch_bounds__(256) void treduce_kernel(float* __restrict__ C) {
    const int b = blockIdx.x >> 2, q = blockIdx.x & 3;
    int rem = b, d = 31;
    while (rem >= 32 - d) { rem -= 32 - d; --d; }   // d: 31..16
    const int bi = rem, bj = bi + d;
    const int i0 = bi * 128, j0 = bj * 128;
    float* T  = C + (size_t)i0 * NDIM + j0;   // true tile (khalf-1 partial)
    float* Mr = C + (size_t)j0 * NDIM + i0;   // mirror (khalf-0 partial)
    const int tid = threadIdx.x;
    const f32x4 z = {0.f, 0.f, 0.f, 0.f};
    #pragma unroll
    for (int t = 0; t < 4; ++t) {
        int e  = (t * 256 + tid) * 4;
        int rr = q * 32 + (e >> 7), cc = e & 127;
        f32x4 p = __builtin_nontemporal_load((const f32x4*)(Mr + (size_t)rr * NDIM + cc));
        f32x4 v = *(const f32x4*)(T + (size_t)rr * NDIM + cc);
        v = v + p;
        __builtin_nontemporal_store(v, (f32x4*)(T + (size_t)rr * NDIM + cc));
        __builtin_nontemporal_store(z, (f32x4*)(Mr + (size_t)rr * NDIM + cc));
    }
}

extern "C" void kernel_launch(void* const* d_in, const int* in_sizes, int n_in,
                              void* d_out, int out_size, void* d_ws, size_t ws_size,
                              hipStream_t stream) {
    const float* A = (const float*)d_in[0];
    const float* B = (const float*)d_in[1];
    float* C = (float*)d_out;

    // Packed panels: 1056 steps x 16 KB each = 16.5 MB per operand
    unsigned short* Abf = (unsigned short*)d_ws;
    unsigned short* Bt  = Abf + (size_t)1056 * STEP_SHORTS;

    // 528 A-tiles + 1056 B-step-blocks
    prep_kernel<<<1584, 256, 0, stream>>>(A, B, Abf, Bt);
    // sum over bj: (bj+1) + max(0,bj-15) = 528 + 136 = 664 blocks
    trigemm_kernel<<<664, 256, 0, stream>>>(Abf, Bt, C);
    // 136 split tiles x 4 quarters
    treduce_kernel<<<544, 256, 0, stream>>>(C);
}

// Round 5
// 206.129 us; speedup vs baseline: 1.6731x; 1.0192x over previous
//
#include <hip/hip_runtime.h>
#include <hip/hip_bf16.h>
#include <stdint.h>

#define NDIM 4096
#define BM 128
#define BN 128
#define BK 64              // K-step: 128 rows x 64 k x bf16 = 16 KB panel chunk
#define STEP_SHORTS 8192   // shorts per packed panel step-chunk

typedef __attribute__((ext_vector_type(8))) short bf16x8;
typedef __attribute__((ext_vector_type(8))) unsigned short u16x8;
typedef __attribute__((ext_vector_type(4))) float f32x4;

__device__ __forceinline__ unsigned short f2bf(float f) {
    union { float f; uint32_t u; } v; v.f = f;
    uint32_t u = v.u;
    u += 0x7FFFu + ((u >> 16) & 1u);   // round-to-nearest-even
    return (unsigned short)(u >> 16);
}

// Packed panel step bases (in 16KB step-chunks). Chunk layout = row-major
// [128 rows][64 k] bf16 (verified R4: staging reads it as tid*16B).
// A panel bi: k in [128*bi, 4096) -> 64-2*bi steps. Total 1056 steps = 16.5 MB.
__device__ __forceinline__ int stepbase_A(int bi) { return bi * (65 - bi); }
// B panel bj: k in [0, 128*(bj+1)) -> 2*(bj+1) steps. Total 1056 steps.
__device__ __forceinline__ int stepbase_B(int bj) { return bj * (bj + 1); }

// XCD-affinity column groups: greedy-LPT over column step-weight
// W(bj) = (bj+1)(bj+2). Group loads 1472..1522 (avg 1496, +-1.7%).
// Blocks with id%8==x run on XCD x (round-robin dispatch); each B panel is
// then fetched by exactly one XCD and stays hot in its 4MB L2.
__constant__ signed char GCOLS[8][5] = {
    {31, 16,  8,  4,  1},
    {30, 17,  9,  6, -1},
    {29, 18, 10,  7, -1},
    {28, 19, 11,  5,  0},
    {27, 20, 12,  3,  2},
    {26, 21, 13, -1, -1},
    {25, 22, 14, -1, -1},
    {24, 23, 15, -1, -1}};

// --- Prep ---
// blocks [0,512):      A -> triu-masked bf16 packed panels, SEQUENTIAL reads:
//                      block owns 8 consecutive rows, streams k in [128*bi,4096)
// blocks [512,1568):   B 64k x 128c blocks (k-block <= diag of c-block),
//                      LDS-transposed to packed Bt panels (unchanged from R4)
__global__ __launch_bounds__(256) void prep_kernel(const float* __restrict__ A,
                                                   const float* __restrict__ B,
                                                   unsigned short* __restrict__ Abf,
                                                   unsigned short* __restrict__ Bt) {
    __shared__ float lds[32 * 65];
    const int b   = blockIdx.x;
    const int tid = threadIdx.x;

    if (b < 512) {
        // A rows 8b..8b+7 (b=0 gets the longest rows -> natural LPT)
        const int th   = tid & 31;          // 32 threads per row
        const int rr   = tid >> 5;          // 0..7
        const int r    = b * 8 + rr;
        const int bi   = r >> 7;
        const int rloc = r & 127;
        const int L    = (32 - bi) * 128;   // floats in this row's panel range
        const float* Arow = A + (size_t)r * NDIM + bi * 128;
        unsigned short* P = Abf + (size_t)stepbase_A(bi) * STEP_SHORTS + rloc * 64;
        const int nch = (33 - bi) >> 1;     // 256-float chunks (last may be half)
        for (int c2 = 0; c2 < nch; ++c2) {
            const int ko = c2 * 256 + th * 8;
            if (ko < L) {
                f32x4 v0 = __builtin_nontemporal_load((const f32x4*)(Arow + ko));
                f32x4 v1 = __builtin_nontemporal_load((const f32x4*)(Arow + ko + 4));
                u16x8 o;
                if (ko < 128) {             // diagonal tile: mask k >= r
                    #pragma unroll
                    for (int j = 0; j < 8; ++j) {
                        float f = (j < 4) ? v0[j] : v1[j - 4];
                        o[j] = (ko + j >= rloc) ? f2bf(f) : (unsigned short)0;
                    }
                } else {
                    #pragma unroll
                    for (int j = 0; j < 8; ++j) {
                        float f = (j < 4) ? v0[j] : v1[j - 4];
                        o[j] = f2bf(f);
                    }
                }
                const int s = ko >> 6;
                *(u16x8*)(P + (size_t)s * STEP_SHORTS + (ko & 63)) = o;
            }
        }
    } else {
        // B block: 64 k-rows x 128 c-cols -> panel-B[cb] step (tb), transposed
        int tb = b - 512, cb = 0;
        while (tb >= 2 * (cb + 1)) { tb -= 2 * (cb + 1); ++cb; }
        const int k0 = tb * 64;
        const int c0 = cb * 128;
        const size_t sb = (size_t)(stepbase_B(cb) + tb) * STEP_SHORTS;
        #pragma unroll
        for (int s = 0; s < 4; ++s) {
            int c0s = c0 + s * 32;
            #pragma unroll
            for (int p = 0; p < 2; ++p) {
                int kr = p * 32 + (tid >> 3);
                int cc = (tid & 7) * 4;
                f32x4 v = __builtin_nontemporal_load(
                    (const f32x4*)(B + (size_t)(k0 + kr) * NDIM + c0s + cc));
                lds[(cc + 0) * 65 + kr] = v.x;
                lds[(cc + 1) * 65 + kr] = v.y;
                lds[(cc + 2) * 65 + kr] = v.z;
                lds[(cc + 3) * 65 + kr] = v.w;
            }
            __syncthreads();
            int c  = tid >> 3;
            int ks = (tid & 7) * 8;
            u16x8 o;
            #pragma unroll
            for (int j = 0; j < 8; ++j) {
                float f = lds[c * 65 + ks + j];
                o[j] = (k0 + ks + j <= c0s + c) ? f2bf(f) : (unsigned short)0;
            }
            *(u16x8*)(Bt + sb + s * 2048 + tid * 8) = o;
            __syncthreads();
        }
    }
}

// --- Triangular bf16 MFMA GEMM on packed panels, XCD-affine schedule ---
// Block id -> (XCD group x = id%8, j = id/8) -> walk group's column list.
// Within a column: split halves first (d>=16, longest), then unsplit d desc.
// Split tiles: khalf 1 -> true tile, khalf 0 -> partial into mirror (bj,bi).
__global__ __launch_bounds__(256, 2) void trigemm_kernel(
        const unsigned short* __restrict__ Abf,
        const unsigned short* __restrict__ Bt,
        float* __restrict__ C) {
    {
    }
    const int x = blockIdx.x & 7;
    int j = blockIdx.x >> 3;
    int bj = -1, rank = 0;
    #pragma unroll
    for (int t = 0; t < 5; ++t) {
        int c = GCOLS[x][t];
        if (c < 0) break;
        int n = (c + 1) + (c >= 16 ? c - 15 : 0);
        if (j < n) { bj = c; rank = j; break; }
        j -= n;
    }
    if (bj < 0) return;                      // pad block (24 of 688)

    const int nsplit = (bj >= 16) ? (bj - 15) : 0;
    int bi, khalf, split;
    if (rank < 2 * nsplit) { bi = rank >> 1; khalf = rank & 1; split = 1; }
    else                   { bi = rank - nsplit; khalf = 0; split = 0; }
    const int d = bj - bi;
    const int nsteps = split ? (d + 1) : 2 * (d + 1);   // 2..32

    __shared__ unsigned short As[BM * BK];   // 16 KB
    __shared__ unsigned short Bs[BN * BK];   // 16 KB

    const int tid  = threadIdx.x;
    const int wave = tid >> 6, lane = tid & 63;
    const int wm = wave >> 1, wn = wave & 1;
    const int m_l = lane & 15, kh = lane >> 4;
    const int ml7 = m_l & 7;

    f32x4 acc[4][4] = {};

    const int i0 = bi * BM, j0 = bj * BN;

    const unsigned short* ArS = Abf
        + ((size_t)(stepbase_A(bi) + khalf * (d + 1))) * STEP_SHORTS
        + (size_t)tid * 8;
    const unsigned short* BrS = Bt
        + ((size_t)(stepbase_B(bj) + 2 * bi + khalf * (d + 1))) * STEP_SHORTS
        + (size_t)tid * 8;

    // LDS scatter map (verified): row r0 = tid>>3, chunk kc = tid&7
    const int r0 = tid >> 3, kc = tid & 7;
    const int woff = r0 * BK + ((kc ^ (r0 & 7)) * 8);

    u16x8 a0_0, a0_1, a0_2, a0_3, b0_0, b0_1, b0_2, b0_3;
    u16x8 a1_0, a1_1, a1_2, a1_3, b1_0, b1_1, b1_2, b1_3;

#define LOAD_STAGE(AN, BN_, s) do {                                             \
        const size_t _o = (size_t)(s) * STEP_SHORTS;                            \
        AN##_0 = *(const u16x8*)(ArS + _o);                                     \
        AN##_1 = *(const u16x8*)(ArS + _o + 2048);                              \
        AN##_2 = *(const u16x8*)(ArS + _o + 4096);                              \
        AN##_3 = *(const u16x8*)(ArS + _o + 6144);                              \
        BN_##_0 = *(const u16x8*)(BrS + _o);                                    \
        BN_##_1 = *(const u16x8*)(BrS + _o + 2048);                             \
        BN_##_2 = *(const u16x8*)(BrS + _o + 4096);                             \
        BN_##_3 = *(const u16x8*)(BrS + _o + 6144);                             \
    } while (0)

#define WRITE_STAGE(AN, BN_) do {                                               \
        *(u16x8*)&As[woff         ] = AN##_0;                                   \
        *(u16x8*)&As[woff + 1*2048] = AN##_1;                                   \
        *(u16x8*)&As[woff + 2*2048] = AN##_2;                                   \
        *(u16x8*)&As[woff + 3*2048] = AN##_3;                                   \
        *(u16x8*)&Bs[woff         ] = BN_##_0;                                  \
        *(u16x8*)&Bs[woff + 1*2048] = BN_##_1;                                  \
        *(u16x8*)&Bs[woff + 2*2048] = BN_##_2;                                  \
        *(u16x8*)&Bs[woff + 3*2048] = BN_##_3;                                  \
    } while (0)

#define COMPUTE() do {                                                          \
        _Pragma("unroll")                                                       \
        for (int s = 0; s < 2; ++s) {                                           \
            const int xk = ((s * 4 + kh) ^ ml7) * 8;                            \
            bf16x8 bfr[4], afr[4];                                              \
            _Pragma("unroll")                                                   \
            for (int nt = 0; nt < 4; ++nt)                                      \
                bfr[nt] = *(const bf16x8*)&Bs[(wn*64 + nt*16 + m_l)*BK + xk];   \
            _Pragma("unroll")                                                   \
            for (int mt = 0; mt < 4; ++mt)                                      \
                afr[mt] = *(const bf16x8*)&As[(wm*64 + mt*16 + m_l)*BK + xk];   \
            _Pragma("unroll")                                                   \
            for (int mt = 0; mt < 4; ++mt)                                      \
                _Pragma("unroll")                                               \
                for (int nt = 0; nt < 4; ++nt)                                  \
                    acc[mt][nt] = __builtin_amdgcn_mfma_f32_16x16x32_bf16(      \
                        afr[mt], bfr[nt], acc[mt][nt], 0, 0, 0);                \
        }                                                                       \
    } while (0)

    LOAD_STAGE(a0, b0, 0);
    if (nsteps > 1) LOAD_STAGE(a1, b1, 1);

    int it = 0;
    for (; it + 2 <= nsteps; it += 2) {
        WRITE_STAGE(a0, b0);                 // vmcnt wait: loads issued 2 iters ago
        if (it + 2 < nsteps) LOAD_STAGE(a0, b0, it + 2);
        __syncthreads();
        COMPUTE();
        __syncthreads();
        WRITE_STAGE(a1, b1);
        if (it + 3 < nsteps) LOAD_STAGE(a1, b1, it + 3);
        __syncthreads();
        COMPUTE();
        __syncthreads();
    }
    if (it < nsteps) {                       // odd step-count tail (split halves)
        WRITE_STAGE(a0, b0);
        __syncthreads();
        COMPUTE();
        __syncthreads();
    }
#undef LOAD_STAGE
#undef WRITE_STAGE
#undef COMPUTE

    // Epilogue: C/D layout col=lane&15, row=(lane>>4)*4+reg (m89/m91-verified).
    const bool to_mirror = split && (khalf == 0);
    float* Cbase = to_mirror ? (C + (size_t)j0 * NDIM + i0)
                             : (C + (size_t)i0 * NDIM + j0);
    #pragma unroll
    for (int mt = 0; mt < 4; ++mt)
        #pragma unroll
        for (int nt = 0; nt < 4; ++nt)
            #pragma unroll
            for (int r = 0; r < 4; ++r) {
                int row = wm * 64 + mt * 16 + kh * 4 + r;
                int col = wn * 64 + nt * 16 + m_l;
                __builtin_nontemporal_store(acc[mt][nt][r],
                                            Cbase + (size_t)row * NDIM + col);
            }
    // Mirror zero-fill for unsplit off-diagonal tiles (C is poisoned each call).
    if (!split && bi != bj) {
        float* Z = C + (size_t)j0 * NDIM + i0;
        f32x4 z = {0.f, 0.f, 0.f, 0.f};
        #pragma unroll
        for (int t = 0; t < 16; ++t) {
            int off = (t * 256 + tid) * 4;
            int rr = off >> 7, cc = off & 127;
            __builtin_nontemporal_store(z, (f32x4*)(Z + (size_t)rr * NDIM + cc));
        }
    }
}

// --- Merge split-tile partials: C[true] += C[mirror]; C[mirror] = 0 ---
// 136 split tiles (d >= 16), 4 blocks per tile (32-row quarter each).
__global__ __launch_bounds__(256) void treduce_kernel(float* __restrict__ C) {
    const int b = blockIdx.x >> 2, q = blockIdx.x & 3;
    int rem = b, d = 31;
    while (rem >= 32 - d) { rem -= 32 - d; --d; }   // d: 31..16
    const int bi = rem, bj = bi + d;
    const int i0 = bi * 128, j0 = bj * 128;
    float* T  = C + (size_t)i0 * NDIM + j0;   // true tile (khalf-1 partial)
    float* Mr = C + (size_t)j0 * NDIM + i0;   // mirror (khalf-0 partial)
    const int tid = threadIdx.x;
    const f32x4 z = {0.f, 0.f, 0.f, 0.f};
    #pragma unroll
    for (int t = 0; t < 4; ++t) {
        int e  = (t * 256 + tid) * 4;
        int rr = q * 32 + (e >> 7), cc = e & 127;
        f32x4 p = __builtin_nontemporal_load((const f32x4*)(Mr + (size_t)rr * NDIM + cc));
        f32x4 v = *(const f32x4*)(T + (size_t)rr * NDIM + cc);
        v = v + p;
        __builtin_nontemporal_store(v, (f32x4*)(T + (size_t)rr * NDIM + cc));
        __builtin_nontemporal_store(z, (f32x4*)(Mr + (size_t)rr * NDIM + cc));
    }
}

extern "C" void kernel_launch(void* const* d_in, const int* in_sizes, int n_in,
                              void* d_out, int out_size, void* d_ws, size_t ws_size,
                              hipStream_t stream) {
    const float* A = (const float*)d_in[0];
    const float* B = (const float*)d_in[1];
    float* C = (float*)d_out;

    // Packed panels: 1056 steps x 16 KB each = 16.5 MB per operand
    unsigned short* Abf = (unsigned short*)d_ws;
    unsigned short* Bt  = Abf + (size_t)1056 * STEP_SHORTS;

    // 512 A row-strip blocks + 1056 B step-blocks
    prep_kernel<<<1568, 256, 0, stream>>>(A, B, Abf, Bt);
    // 8 XCD groups x 86 slots (664 real blocks + 24 pad)
    trigemm_kernel<<<688, 256, 0, stream>>>(Abf, Bt, C);
    // 136 split tiles x 4 quarters
    treduce_kernel<<<544, 256, 0, stream>>>(C);
}

// Round 6
// 205.586 us; speedup vs baseline: 1.6775x; 1.0026x over previous
//
#include <hip/hip_runtime.h>
#include <hip/hip_bf16.h>
#include <stdint.h>

#define NDIM 4096
#define BM 128
#define BN 128
#define BK 64              // K-step: 128 rows x 64 k x bf16 = 16 KB panel chunk
#define STEP_SHORTS 8192   // shorts per packed panel step-chunk

typedef __attribute__((ext_vector_type(8))) short bf16x8;
typedef __attribute__((ext_vector_type(8))) unsigned short u16x8;
typedef __attribute__((ext_vector_type(4))) float f32x4;

__device__ __forceinline__ unsigned short f2bf(float f) {
    union { float f; uint32_t u; } v; v.f = f;
    uint32_t u = v.u;
    u += 0x7FFFu + ((u >> 16) & 1u);   // round-to-nearest-even
    return (unsigned short)(u >> 16);
}

// Packed panel step bases (in 16KB step-chunks). Chunk layout = [128 r][64 k]
// bf16 row-major (verified R4/R5: trigemm stages it as tid*16B).
// A panel bi: k in [128*bi, 4096) -> 64-2*bi steps. Total 1056 steps = 16.5 MB.
__device__ __forceinline__ int stepbase_A(int bi) { return bi * (65 - bi); }
// B panel bj: k in [0, 128*(bj+1)) -> 2*(bj+1) steps. Total 1056 steps.
__device__ __forceinline__ int stepbase_B(int bj) { return bj * (bj + 1); }

// XCD-affinity column groups: greedy-LPT over column step-weight
// W(bj) = (bj+1)(bj+2). Group loads 1472..1522 (avg 1496, +-1.7%).
// Blocks with id%8==x run on XCD x (round-robin dispatch); each B panel is
// then fetched by exactly one XCD and stays hot in its 4MB L2. (R5: verified
// -44MB FETCH.)
__constant__ signed char GCOLS[8][5] = {
    {31, 16,  8,  4,  1},
    {30, 17,  9,  6, -1},
    {29, 18, 10,  7, -1},
    {28, 19, 11,  5,  0},
    {27, 20, 12,  3,  2},
    {26, 21, 13, -1, -1},
    {25, 22, 14, -1, -1},
    {24, 23, 15, -1, -1}};

// --- Prep ---
// blocks [0,512):      A -> triu-masked bf16 packed panels; block owns 8
//                      consecutive rows, streams k in [128*bi,4096) (sequential)
// blocks [512,1568):   B 64k x 128c block -> one packed Bt step-chunk.
//                      R6: reads 512B-contiguous row segments (16 rows x 128
//                      cols per pass, 4 passes) into padded LDS, ONE sync,
//                      then masked cvt + packed write. (R5 read 128B strided.)
__global__ __launch_bounds__(256) void prep_kernel(const float* __restrict__ A,
                                                   const float* __restrict__ B,
                                                   unsigned short* __restrict__ Abf,
                                                   unsigned short* __restrict__ Bt) {
    __shared__ float lds[64 * 129];          // [k][c] padded: +1 row-pad
    const int b   = blockIdx.x;
    const int tid = threadIdx.x;

    if (b < 512) {
        // A rows 8b..8b+7 (b=0 gets the longest rows -> natural LPT)
        const int th   = tid & 31;          // 32 threads per row
        const int rr   = tid >> 5;          // 0..7
        const int r    = b * 8 + rr;
        const int bi   = r >> 7;            // same for all 8 rows (128%8==0)
        const int rloc = r & 127;
        const int L    = (32 - bi) * 128;   // floats in this row's panel range
        const float* Arow = A + (size_t)r * NDIM + bi * 128;
        unsigned short* P = Abf + (size_t)stepbase_A(bi) * STEP_SHORTS + rloc * 64;
        const int nch = (33 - bi) >> 1;     // 256-float chunks
        for (int c2 = 0; c2 < nch; ++c2) {
            const int ko = c2 * 256 + th * 8;
            if (ko < L) {
                f32x4 v0 = __builtin_nontemporal_load((const f32x4*)(Arow + ko));
                f32x4 v1 = __builtin_nontemporal_load((const f32x4*)(Arow + ko + 4));
                u16x8 o;
                if (ko < 128) {             // diagonal tile: mask k >= r
                    #pragma unroll
                    for (int j = 0; j < 8; ++j) {
                        float f = (j < 4) ? v0[j] : v1[j - 4];
                        o[j] = (ko + j >= rloc) ? f2bf(f) : (unsigned short)0;
                    }
                } else {
                    #pragma unroll
                    for (int j = 0; j < 8; ++j) {
                        float f = (j < 4) ? v0[j] : v1[j - 4];
                        o[j] = f2bf(f);
                    }
                }
                const int s = ko >> 6;
                *(u16x8*)(P + (size_t)s * STEP_SHORTS + (ko & 63)) = o;
            }
        }
    } else {
        // B block: 64 k-rows x 128 c-cols -> packed Bt step (tb of panel cb)
        int tb = b - 512, cb = 0;
        while (tb >= 2 * (cb + 1)) { tb -= 2 * (cb + 1); ++cb; }
        const int k0 = tb * 64;
        const int c0 = cb * 128;
        const size_t sb = (size_t)(stepbase_B(cb) + tb) * STEP_SHORTS;

        // 4 passes: 16 rows x 128 cols each; 512B contiguous per row segment
        #pragma unroll
        for (int p = 0; p < 4; ++p) {
            const int kr = p * 16 + (tid >> 4);     // k-row 0..63
            const int cc = (tid & 15) * 8;          // col 0..120 step 8
            const float* src = B + (size_t)(k0 + kr) * NDIM + c0 + cc;
            f32x4 v0 = __builtin_nontemporal_load((const f32x4*)src);
            f32x4 v1 = __builtin_nontemporal_load((const f32x4*)(src + 4));
            float* dst = &lds[kr * 129 + cc];
            *(f32x4*)dst       = v0;
            *(f32x4*)(dst + 4) = v1;
        }
        __syncthreads();
        // Emit: thread covers c = s*32 + (tid>>3), k = (tid&7)*8 .. +7
        const int cl = tid >> 3;                    // 0..31 within s-group
        const int ks = (tid & 7) * 8;
        #pragma unroll
        for (int s = 0; s < 4; ++s) {
            const int c = s * 32 + cl;
            u16x8 o;
            #pragma unroll
            for (int j = 0; j < 8; ++j) {
                float f = lds[(ks + j) * 129 + c];  // 2-way banked (pad 129)
                o[j] = (k0 + ks + j <= c0 + c) ? f2bf(f) : (unsigned short)0;
            }
            *(u16x8*)(Bt + sb + s * 2048 + tid * 8) = o;
        }
    }
}

// --- Triangular bf16 MFMA GEMM on packed panels, XCD-affine schedule ---
// Block id -> (XCD group x = id%8, j = id/8) -> walk group's column list.
// Within a column: split halves first (d>=16, longest), then unsplit d desc.
// Split tiles: khalf 1 -> true tile, khalf 0 -> partial into mirror (bj,bi).
__global__ __launch_bounds__(256, 2) void trigemm_kernel(
        const unsigned short* __restrict__ Abf,
        const unsigned short* __restrict__ Bt,
        float* __restrict__ C) {
    const int x = blockIdx.x & 7;
    int j = blockIdx.x >> 3;
    int bj = -1, rank = 0;
    #pragma unroll
    for (int t = 0; t < 5; ++t) {
        int c = GCOLS[x][t];
        if (c < 0) break;
        int n = (c + 1) + (c >= 16 ? c - 15 : 0);
        if (j < n) { bj = c; rank = j; break; }
        j -= n;
    }
    if (bj < 0) return;                      // pad block (24 of 688)

    const int nsplit = (bj >= 16) ? (bj - 15) : 0;
    int bi, khalf, split;
    if (rank < 2 * nsplit) { bi = rank >> 1; khalf = rank & 1; split = 1; }
    else                   { bi = rank - nsplit; khalf = 0; split = 0; }
    const int d = bj - bi;
    const int nsteps = split ? (d + 1) : 2 * (d + 1);   // 2..32

    __shared__ unsigned short As[BM * BK];   // 16 KB
    __shared__ unsigned short Bs[BN * BK];   // 16 KB

    const int tid  = threadIdx.x;
    const int wave = tid >> 6, lane = tid & 63;
    const int wm = wave >> 1, wn = wave & 1;
    const int m_l = lane & 15, kh = lane >> 4;
    const int ml7 = m_l & 7;

    f32x4 acc[4][4] = {};

    const int i0 = bi * BM, j0 = bj * BN;

    const unsigned short* ArS = Abf
        + ((size_t)(stepbase_A(bi) + khalf * (d + 1))) * STEP_SHORTS
        + (size_t)tid * 8;
    const unsigned short* BrS = Bt
        + ((size_t)(stepbase_B(bj) + 2 * bi + khalf * (d + 1))) * STEP_SHORTS
        + (size_t)tid * 8;

    // LDS scatter map (verified): row r0 = tid>>3, chunk kc = tid&7
    const int r0 = tid >> 3, kc = tid & 7;
    const int woff = r0 * BK + ((kc ^ (r0 & 7)) * 8);

    u16x8 a0_0, a0_1, a0_2, a0_3, b0_0, b0_1, b0_2, b0_3;
    u16x8 a1_0, a1_1, a1_2, a1_3, b1_0, b1_1, b1_2, b1_3;

#define LOAD_STAGE(AN, BN_, s) do {                                             \
        const size_t _o = (size_t)(s) * STEP_SHORTS;                            \
        AN##_0 = *(const u16x8*)(ArS + _o);                                     \
        AN##_1 = *(const u16x8*)(ArS + _o + 2048);                              \
        AN##_2 = *(const u16x8*)(ArS + _o + 4096);                              \
        AN##_3 = *(const u16x8*)(ArS + _o + 6144);                              \
        BN_##_0 = *(const u16x8*)(BrS + _o);                                    \
        BN_##_1 = *(const u16x8*)(BrS + _o + 2048);                             \
        BN_##_2 = *(const u16x8*)(BrS + _o + 4096);                             \
        BN_##_3 = *(const u16x8*)(BrS + _o + 6144);                             \
    } while (0)

#define WRITE_STAGE(AN, BN_) do {                                               \
        *(u16x8*)&As[woff         ] = AN##_0;                                   \
        *(u16x8*)&As[woff + 1*2048] = AN##_1;                                   \
        *(u16x8*)&As[woff + 2*2048] = AN##_2;                                   \
        *(u16x8*)&As[woff + 3*2048] = AN##_3;                                   \
        *(u16x8*)&Bs[woff         ] = BN_##_0;                                  \
        *(u16x8*)&Bs[woff + 1*2048] = BN_##_1;                                  \
        *(u16x8*)&Bs[woff + 2*2048] = BN_##_2;                                  \
        *(u16x8*)&Bs[woff + 3*2048] = BN_##_3;                                  \
    } while (0)

#define COMPUTE() do {                                                          \
        _Pragma("unroll")                                                       \
        for (int s = 0; s < 2; ++s) {                                           \
            const int xk = ((s * 4 + kh) ^ ml7) * 8;                            \
            bf16x8 bfr[4], afr[4];                                              \
            _Pragma("unroll")                                                   \
            for (int nt = 0; nt < 4; ++nt)                                      \
                bfr[nt] = *(const bf16x8*)&Bs[(wn*64 + nt*16 + m_l)*BK + xk];   \
            _Pragma("unroll")                                                   \
            for (int mt = 0; mt < 4; ++mt)                                      \
                afr[mt] = *(const bf16x8*)&As[(wm*64 + mt*16 + m_l)*BK + xk];   \
            _Pragma("unroll")                                                   \
            for (int mt = 0; mt < 4; ++mt)                                      \
                _Pragma("unroll")                                               \
                for (int nt = 0; nt < 4; ++nt)                                  \
                    acc[mt][nt] = __builtin_amdgcn_mfma_f32_16x16x32_bf16(      \
                        afr[mt], bfr[nt], acc[mt][nt], 0, 0, 0);                \
        }                                                                       \
    } while (0)

    LOAD_STAGE(a0, b0, 0);
    if (nsteps > 1) LOAD_STAGE(a1, b1, 1);

    int it = 0;
    for (; it + 2 <= nsteps; it += 2) {
        WRITE_STAGE(a0, b0);                 // vmcnt wait: loads issued 2 iters ago
        if (it + 2 < nsteps) LOAD_STAGE(a0, b0, it + 2);
        __syncthreads();
        COMPUTE();
        __syncthreads();
        WRITE_STAGE(a1, b1);
        if (it + 3 < nsteps) LOAD_STAGE(a1, b1, it + 3);
        __syncthreads();
        COMPUTE();
        __syncthreads();
    }
    if (it < nsteps) {                       // odd step-count tail (split halves)
        WRITE_STAGE(a0, b0);
        __syncthreads();
        COMPUTE();
        __syncthreads();
    }
#undef LOAD_STAGE
#undef WRITE_STAGE
#undef COMPUTE

    // Epilogue: C/D layout col=lane&15, row=(lane>>4)*4+reg (m89/m91-verified).
    const bool to_mirror = split && (khalf == 0);
    float* Cbase = to_mirror ? (C + (size_t)j0 * NDIM + i0)
                             : (C + (size_t)i0 * NDIM + j0);
    #pragma unroll
    for (int mt = 0; mt < 4; ++mt)
        #pragma unroll
        for (int nt = 0; nt < 4; ++nt)
            #pragma unroll
            for (int r = 0; r < 4; ++r) {
                int row = wm * 64 + mt * 16 + kh * 4 + r;
                int col = wn * 64 + nt * 16 + m_l;
                __builtin_nontemporal_store(acc[mt][nt][r],
                                            Cbase + (size_t)row * NDIM + col);
            }
    // Mirror zero-fill for unsplit off-diagonal tiles (C is poisoned each call).
    if (!split && bi != bj) {
        float* Z = C + (size_t)j0 * NDIM + i0;
        f32x4 z = {0.f, 0.f, 0.f, 0.f};
        #pragma unroll
        for (int t = 0; t < 16; ++t) {
            int off = (t * 256 + tid) * 4;
            int rr = off >> 7, cc = off & 127;
            __builtin_nontemporal_store(z, (f32x4*)(Z + (size_t)rr * NDIM + cc));
        }
    }
}

// --- Merge split-tile partials: C[true] += C[mirror]; C[mirror] = 0 ---
// 136 split tiles (d >= 16), 4 blocks per tile (32-row quarter each).
__global__ __launch_bounds__(256) void treduce_kernel(float* __restrict__ C) {
    const int b = blockIdx.x >> 2, q = blockIdx.x & 3;
    int rem = b, d = 31;
    while (rem >= 32 - d) { rem -= 32 - d; --d; }   // d: 31..16
    const int bi = rem, bj = bi + d;
    const int i0 = bi * 128, j0 = bj * 128;
    float* T  = C + (size_t)i0 * NDIM + j0;   // true tile (khalf-1 partial)
    float* Mr = C + (size_t)j0 * NDIM + i0;   // mirror (khalf-0 partial)
    const int tid = threadIdx.x;
    const f32x4 z = {0.f, 0.f, 0.f, 0.f};
    #pragma unroll
    for (int t = 0; t < 4; ++t) {
        int e  = (t * 256 + tid) * 4;
        int rr = q * 32 + (e >> 7), cc = e & 127;
        f32x4 p = __builtin_nontemporal_load((const f32x4*)(Mr + (size_t)rr * NDIM + cc));
        f32x4 v = *(const f32x4*)(T + (size_t)rr * NDIM + cc);
        v = v + p;
        __builtin_nontemporal_store(v, (f32x4*)(T + (size_t)rr * NDIM + cc));
        __builtin_nontemporal_store(z, (f32x4*)(Mr + (size_t)rr * NDIM + cc));
    }
}

extern "C" void kernel_launch(void* const* d_in, const int* in_sizes, int n_in,
                              void* d_out, int out_size, void* d_ws, size_t ws_size,
                              hipStream_t stream) {
    const float* A = (const float*)d_in[0];
    const float* B = (const float*)d_in[1];
    float* C = (float*)d_out;

    // Packed panels: 1056 steps x 16 KB each = 16.5 MB per operand
    unsigned short* Abf = (unsigned short*)d_ws;
    unsigned short* Bt  = Abf + (size_t)1056 * STEP_SHORTS;

    // 512 A row-strip blocks + 1056 B step-blocks
    prep_kernel<<<1568, 256, 0, stream>>>(A, B, Abf, Bt);
    // 8 XCD groups x 86 slots (664 real blocks + 24 pad)
    trigemm_kernel<<<688, 256, 0, stream>>>(Abf, Bt, C);
    // 136 split tiles x 4 quarters
    treduce_kernel<<<544, 256, 0, stream>>>(C);
}